// Round 5
// baseline (257.397 us; speedup 1.0000x reference)
//
#include <hip/hip_runtime.h>

#define Bb 32
#define Nn 512
#define Dd 256
#define KC 1792   // 256 (self) + 6*256 (edge types)

typedef __bf16 bf16x8 __attribute__((ext_vector_type(8)));
typedef float  f32x4  __attribute__((ext_vector_type(4)));
typedef unsigned short u16;

__device__ __forceinline__ u16 f2bf(float x){
  union { float f; unsigned u; } c; c.f = x;
  unsigned u = c.u;
  u += 0x7FFFu + ((u >> 16) & 1u);   // RNE
  return (u16)(u >> 16);
}

// ---------------- K0: WcatT[e][c] = Wcat[c][e] in bf16, [256 x 1792] -------
__global__ __launch_bounds__(256) void k_prep(
    const float* __restrict__ wself,
    const float* __restrict__ w0, const float* __restrict__ w1,
    const float* __restrict__ w2, const float* __restrict__ w3,
    const float* __restrict__ w4, const float* __restrict__ w5,
    u16* __restrict__ wcatT){
  int e = blockIdx.x;
  const float* Ws[7] = {wself, w0, w1, w2, w3, w4, w5};
  for (int c = threadIdx.x; c < KC; c += 256){
    int g = c >> 8, j = c & 255;
    wcatT[(size_t)e*KC + c] = f2bf(Ws[g][j*Dd + e]);
  }
}

// ---------------- K1: bitpack graphs (mask+diag folded) + nn popcount ------
// Block = 2 rows x 6 graphs. Thread owns one 4-col nibble per graph:
// 7 independent int4 loads, ~10 VALU each, ds_write_b8. No shuffles/ballots.
// 192 packer threads then assemble 32-bit words from 8 LDS nibble-bytes.
// Gp[k][b][m][w]: bit j of word w = masked G value at col 32w+j (unchanged).
__global__ __launch_bounds__(256) void k_pack(
    const int* __restrict__ g0, const int* __restrict__ g1,
    const int* __restrict__ g2, const int* __restrict__ g3,
    const int* __restrict__ g4, const int* __restrict__ g5,
    const int* __restrict__ mask, unsigned* __restrict__ Gp,
    float* __restrict__ rs){
  __shared__ unsigned char nibs[12][128];   // [k*2+half][chunk]
  __shared__ int reds[4];
  int t = threadIdx.x;
  int half = t >> 7, c = t & 127;           // chunk c covers cols 4c..4c+3
  int R = blockIdx.x * 2;                   // rows R, R+1 (same batch)
  int r = R + half, b = R >> 9, m = r & 511;

  const int4* mrow4 = (const int4*)(mask + (size_t)b * Nn);
  size_t gi = (size_t)r * 128 + c;          // int4 index into graph row
  int4 mm  = mrow4[c];
  int4 a0 = ((const int4*)g0)[gi];
  int4 a1 = ((const int4*)g1)[gi];
  int4 a2 = ((const int4*)g2)[gi];
  int4 a3 = ((const int4*)g3)[gi];
  int4 a4 = ((const int4*)g4)[gi];
  int4 a5 = ((const int4*)g5)[gi];

  unsigned dm = (c == (m >> 2)) ? (1u << (m & 3)) : 0u;  // diagonal bit
  int stot = 0;
#define DO_K(k, g)                                                         \
  {                                                                        \
    unsigned nib = (unsigned)((g.x & mm.x) | ((g.y & mm.y) << 1) |         \
                              ((g.z & mm.z) << 2) | ((g.w & mm.w) << 3));  \
    nib &= ~dm;                                                            \
    stot += __popc(nib);                                                   \
    nibs[k * 2 + half][c] = (unsigned char)nib;                           \
  }
  DO_K(0, a0) DO_K(1, a1) DO_K(2, a2) DO_K(3, a3) DO_K(4, a4) DO_K(5, a5)
#undef DO_K

  // wave-reduce stot (each wave is row-uniform: waves 0,1 -> row A; 2,3 -> B)
  #pragma unroll
  for (int off = 1; off < 64; off <<= 1) stot += __shfl_xor(stot, off);
  if ((t & 63) == 0) reds[t >> 6] = stot;
  __syncthreads();

  if (t < 192){
    int rg = t >> 4, w = t & 15;            // rg = k*2+half2, word w
    int k = rg >> 1, h2 = rg & 1;
    unsigned d0 = *(const unsigned*)&nibs[rg][w * 8];
    unsigned d1 = *(const unsigned*)&nibs[rg][w * 8 + 4];
    unsigned x0 = (d0 | (d0 >> 4)) & 0x00FF00FFu; x0 = (x0 | (x0 >> 8)) & 0xFFFFu;
    unsigned x1 = (d1 | (d1 >> 4)) & 0x00FF00FFu; x1 = (x1 | (x1 >> 8)) & 0xFFFFu;
    Gp[((size_t)k * Bb * Nn + (R + h2)) * 16 + w] = x0 | (x1 << 16);
  } else if (t < 194){
    int h2 = t - 192;
    int s = reds[h2 * 2] + reds[h2 * 2 + 1];
    rs[R + h2] = mask[R + h2] ? 1.0f / (float)(s < 1 ? 1 : s) : 0.0f;
  }
}

// ---------------- K2: dw (sigmoid), Z node copy (bf16), X'^T build ---------
__global__ __launch_bounds__(256) void k_dw(
    const float* __restrict__ node, const int* __restrict__ mask,
    const float* __restrict__ wnw, const float* __restrict__ bnw,
    float* __restrict__ aw_out,    // already offset by t*N
    u16* __restrict__ Z, u16* __restrict__ XT){
  __shared__ float tile[32][268];
  __shared__ float dws[32];
  int b = blockIdx.x >> 4, n0 = (blockIdx.x & 15) << 5;
  int t = threadIdx.x;
  int row = t >> 3, seg = t & 7;
  const float* src = node + ((size_t)(b * Nn + n0 + row)) * Dd + seg * 32;
  u16* zn = Z + ((size_t)(b * Nn + n0 + row)) * KC + seg * 32;
  #pragma unroll
  for (int c = 0; c < 8; ++c){
    float4 v = ((const float4*)src)[c];
    tile[row][seg * 32 + c * 4 + 0] = v.x;
    tile[row][seg * 32 + c * 4 + 1] = v.y;
    tile[row][seg * 32 + c * 4 + 2] = v.z;
    tile[row][seg * 32 + c * 4 + 3] = v.w;
    ushort4 h;
    h.x = f2bf(v.x); h.y = f2bf(v.y); h.z = f2bf(v.z); h.w = f2bf(v.w);
    ((ushort4*)zn)[c] = h;
  }
  __syncthreads();
  float s = 0.f;
  #pragma unroll
  for (int c = 0; c < 32; ++c) s += tile[row][seg * 32 + c] * wnw[seg * 32 + c];
  s += __shfl_xor(s, 1); s += __shfl_xor(s, 2); s += __shfl_xor(s, 4);
  if (seg == 0){
    float dw = 1.f / (1.f + expf(-(s + bnw[0])));
    aw_out[b * (2 * Nn) + n0 + row] = dw;
    dws[row] = mask[b * Nn + n0 + row] ? dw : 0.f;
  }
  __syncthreads();
  #pragma unroll
  for (int p = 0; p < 4; ++p){
    int d = p * 64 + (t >> 2);
    int j0 = (t & 3) * 8;
    union { u16 h[8]; uint4 v; } pk;
    #pragma unroll
    for (int jj = 0; jj < 8; ++jj)
      pk.h[jj] = f2bf(dws[j0 + jj] * tile[j0 + jj][d]);
    *(uint4*)(XT + ((size_t)(b * Dd + d)) * Nn + n0 + j0) = pk.v;
  }
}

// ---------------- K3: aggregation GEMM  H'_k = rs * (G_k @ X') ------------
// grid (8, 32, 6): mtile, b, edge-type.  BM=64, BN=256(full D), BK=64, 4 waves
__global__ __launch_bounds__(256) void k_agg(
    const unsigned* __restrict__ Gp,
    const u16* __restrict__ XT, const float* __restrict__ rs,
    u16* __restrict__ Z){
  int mt = blockIdx.x, b = blockIdx.y, kg = blockIdx.z;
  int m0 = mt * 64;
  const unsigned* Gr = Gp + ((size_t)kg * Bb * Nn + b * Nn + m0) * 16;
  const u16* Xb = XT + (size_t)b * Dd * Nn;
  __shared__ u16 As[64 * 72];
  __shared__ u16 Bs[256 * 72];
  int t = threadIdx.x, lane = t & 63, wn = t >> 6;
  int arow = t >> 2, aq = t & 3;
  // preload this thread's 8 packed words (one per K-step), L2-hit
  unsigned wpre[8];
  #pragma unroll
  for (int ks = 0; ks < 8; ++ks)
    wpre[ks] = Gr[arow * 16 + ks * 2 + (aq >> 1)];

  f32x4 acc[4][4];
  #pragma unroll
  for (int i = 0; i < 4; ++i)
    #pragma unroll
    for (int q = 0; q < 4; ++q) acc[i][q] = (f32x4){0.f, 0.f, 0.f, 0.f};

  for (int ks = 0; ks < 8; ++ks){
    int k0 = ks * 64;
    { // A stage: unpack 16 bits -> bf16 0/1
      unsigned bits = (wpre[ks] >> ((aq & 1) * 16)) & 0xFFFFu;
      union { u16 h[16]; uint4 v[2]; } pk;
      #pragma unroll
      for (int c = 0; c < 16; ++c)
        pk.h[c] = ((bits >> c) & 1u) ? 0x3F80 : 0;
      *(uint4*)&As[arow * 72 + aq * 16]     = pk.v[0];
      *(uint4*)&As[arow * 72 + aq * 16 + 8] = pk.v[1];
    }
    // B stage: 256 rows (d) x 64 cols (n-slice) from X'^T
    #pragma unroll
    for (int p = 0; p < 8; ++p){
      int rowb = p * 32 + (t >> 3);
      *(uint4*)&Bs[rowb * 72 + (t & 7) * 8] =
          *(const uint4*)(Xb + (size_t)rowb * Nn + k0 + (t & 7) * 8);
    }
    __syncthreads();
    #pragma unroll
    for (int kk = 0; kk < 2; ++kk){
      bf16x8 av[4], bv[4];
      #pragma unroll
      for (int i = 0; i < 4; ++i)
        av[i] = *(const bf16x8*)&As[(i * 16 + (lane & 15)) * 72 + kk * 32 + (lane >> 4) * 8];
      #pragma unroll
      for (int q = 0; q < 4; ++q)
        bv[q] = *(const bf16x8*)&Bs[(wn * 64 + q * 16 + (lane & 15)) * 72 + kk * 32 + (lane >> 4) * 8];
      #pragma unroll
      for (int i = 0; i < 4; ++i)
        #pragma unroll
        for (int q = 0; q < 4; ++q)
          acc[i][q] = __builtin_amdgcn_mfma_f32_16x16x32_bf16(av[i], bv[q], acc[i][q], 0, 0, 0);
    }
    __syncthreads();
  }
  int kgcol = 256 + kg * 256 + wn * 64;
  #pragma unroll
  for (int i = 0; i < 4; ++i){
    #pragma unroll
    for (int r = 0; r < 4; ++r){
      int mg = m0 + i * 16 + (lane >> 4) * 4 + r;
      float sc = rs[b * Nn + mg];
      u16* zp = Z + ((size_t)(b * Nn + mg)) * KC + kgcol + (lane & 15);
      #pragma unroll
      for (int q = 0; q < 4; ++q)
        zp[q * 16] = f2bf(acc[i][q][r] * sc);
    }
  }
}

// ---------------- K4: update GEMM  out = relu(Z @ Wcat + b_self) ----------
// grid (256): mtile. BM=64, BN=256 (full width -> Z read ONCE), BK=64,
// 4 waves as 2x2 (wave = 32 rows x 128 cols)
__global__ __launch_bounds__(256) void k_upd(
    const u16* __restrict__ Z, const u16* __restrict__ wcatT,
    const float* __restrict__ bself, float* __restrict__ outp){
  int m0 = blockIdx.x * 64;
  __shared__ u16 As[64 * 72];
  __shared__ u16 Bs[256 * 72];
  int t = threadIdx.x, lane = t & 63, wid = t >> 6;
  int wm = wid >> 1, wn = wid & 1;
  f32x4 acc[2][8];
  #pragma unroll
  for (int i = 0; i < 2; ++i)
    #pragma unroll
    for (int q = 0; q < 8; ++q) acc[i][q] = (f32x4){0.f, 0.f, 0.f, 0.f};

  for (int ks = 0; ks < 28; ++ks){
    int k0 = ks * 64;
    #pragma unroll
    for (int p = 0; p < 2; ++p){
      int row = p * 32 + (t >> 3);
      *(uint4*)&As[row * 72 + (t & 7) * 8] =
          *(const uint4*)(Z + ((size_t)(m0 + row)) * KC + k0 + (t & 7) * 8);
    }
    #pragma unroll
    for (int p = 0; p < 8; ++p){
      int row = p * 32 + (t >> 3);
      *(uint4*)&Bs[row * 72 + (t & 7) * 8] =
          *(const uint4*)(wcatT + ((size_t)row) * KC + k0 + (t & 7) * 8);
    }
    __syncthreads();
    #pragma unroll
    for (int kk = 0; kk < 2; ++kk){
      bf16x8 av[2], bv[8];
      #pragma unroll
      for (int i = 0; i < 2; ++i)
        av[i] = *(const bf16x8*)&As[(wm * 32 + i * 16 + (lane & 15)) * 72 + kk * 32 + (lane >> 4) * 8];
      #pragma unroll
      for (int q = 0; q < 8; ++q)
        bv[q] = *(const bf16x8*)&Bs[(wn * 128 + q * 16 + (lane & 15)) * 72 + kk * 32 + (lane >> 4) * 8];
      #pragma unroll
      for (int i = 0; i < 2; ++i)
        #pragma unroll
        for (int q = 0; q < 8; ++q)
          acc[i][q] = __builtin_amdgcn_mfma_f32_16x16x32_bf16(av[i], bv[q], acc[i][q], 0, 0, 0);
    }
    __syncthreads();
  }
  #pragma unroll
  for (int i = 0; i < 2; ++i){
    #pragma unroll
    for (int r = 0; r < 4; ++r){
      int mg = m0 + wm * 32 + i * 16 + (lane >> 4) * 4 + r;
      #pragma unroll
      for (int q = 0; q < 8; ++q){
        int e = wn * 128 + q * 16 + (lane & 15);
        float v = acc[i][q][r] + bself[e];
        outp[(size_t)mg * Dd + e] = v > 0.f ? v : 0.f;
      }
    }
  }
}

extern "C" void kernel_launch(void* const* d_in, const int* in_sizes, int n_in,
                              void* d_out, int out_size, void* d_ws, size_t ws_size,
                              hipStream_t stream){
  (void)in_sizes; (void)n_in; (void)out_size; (void)ws_size;
  const float* node  = (const float*)d_in[0];
  const int*   mask  = (const int*)d_in[1];
  const int*   g[6];
  for (int i = 0; i < 6; ++i) g[i] = (const int*)d_in[2 + i];
  const float* wnw   = (const float*)d_in[8];
  const float* bnw   = (const float*)d_in[9];
  const float* wself = (const float*)d_in[10];
  const float* bself = (const float*)d_in[11];
  const float* W[6];
  for (int i = 0; i < 6; ++i) W[i] = (const float*)d_in[12 + i];

  float* out_node = (float*)d_out;
  float* out_aw   = out_node + (size_t)Bb * Nn * Dd;

  char* ws = (char*)d_ws;
  u16*      wcatT = (u16*)(ws);                    // 917,504 B
  float*    rs    = (float*)(ws + 917504);         // 65,536 B
  unsigned* Gp    = (unsigned*)(ws + 1048576);     // 6,291,456 B
  u16*      XT    = (u16*)(ws + 7340032);          // 8,388,608 B
  u16*      Z     = (u16*)(ws + 15728640);         // 58,720,256 B -> ends ~71 MB

  k_prep<<<256, 256, 0, stream>>>(wself, W[0], W[1], W[2], W[3], W[4], W[5], wcatT);
  k_pack<<<8192, 256, 0, stream>>>(g[0], g[1], g[2], g[3], g[4], g[5], mask, Gp, rs);

  for (int t = 0; t < 2; ++t){
    const float* nsrc = (t == 0) ? node : out_node;   // iter-1 result lives in d_out
    k_dw<<<512, 256, 0, stream>>>(nsrc, mask, wnw, bnw, out_aw + t * Nn, Z, XT);
    k_agg<<<dim3(8, 32, 6), 256, 0, stream>>>(Gp, XT, rs, Z);
    k_upd<<<256, 256, 0, stream>>>(Z, wcatT, bself, out_node);
  }
}